// Round 1
// baseline (186.899 us; speedup 1.0000x reference)
//
#include <hip/hip_runtime.h>
#include <hip/hip_fp16.h>
#include <math.h>

// Problem dims
#define B_ 8
#define H_ 640
#define W_ 368
#define HW_ (H_*W_)
#define NP_ (B_*H_*W_)   // 1,884,160

#define FROWS 4          // h-rows per block in fused kbranch+fftW kernel
#define HLINES 4         // (b,w) lines per block in H-axis FFT
#define HP 645           // LDS pitch (float2) for H kernel
#define TS 16            // spatial tile for fused tail kernel

typedef __attribute__((ext_vector_type(8))) short v8s;   // 8 bf16 (4 VGPR)
typedef __attribute__((ext_vector_type(4))) float v4f;   // MFMA acc

__device__ __forceinline__ float leaky_(float x){ return fmaxf(x, 0.01f*x); }

// fp32 -> bf16 round-to-nearest-even
__device__ __forceinline__ unsigned short f2bf(float x){
    unsigned u = __float_as_uint(x);
    u += 0x7FFFu + ((u >> 16) & 1u);
    return (unsigned short)(u >> 16);
}

// pack two fp32 -> bf16x2 dword (RNE), single HW op
__device__ __forceinline__ unsigned cvtpk_(float lo, float hi){
    unsigned r;
    asm("v_cvt_pk_bf16_f32 %0, %1, %2" : "=v"(r) : "v"(lo), "v"(hi));
    return r;
}

__device__ __forceinline__ float2 cadd_(float2 a, float2 b){ return make_float2(a.x+b.x, a.y+b.y); }
__device__ __forceinline__ float2 csub_(float2 a, float2 b){ return make_float2(a.x-b.x, a.y-b.y); }
__device__ __forceinline__ float2 cmul_(float2 a, float c, float s){
    return make_float2(a.x*c - a.y*s, a.x*s + a.y*c);
}
__device__ __forceinline__ float2 cmulv_(float2 a, float2 w){
    return make_float2(a.x*w.x - a.y*w.y, a.x*w.y + a.y*w.x);
}

// DFT4 with +i convention
__device__ __forceinline__ void dft4p_(float2 p0, float2 p1, float2 p2, float2 p3,
                                       float2& z0, float2& z1, float2& z2, float2& z3){
    float2 s0 = cadd_(p0,p2), d0 = csub_(p0,p2);
    float2 s1 = cadd_(p1,p3), d1 = csub_(p1,p3);
    z0 = cadd_(s0,s1);
    z2 = csub_(s0,s1);
    z1 = make_float2(d0.x - d1.y, d0.y + d1.x);
    z3 = make_float2(d0.x + d1.y, d0.y - d1.x);
}

// 16-point DFT, +i convention
__device__ __forceinline__ void fft16p_(const float2* x, float2* X){
    const float C1 = 0.9238795325112867f, S1 = 0.3826834323650898f;
    const float R  = 0.7071067811865476f;
    float2 Y[4][4];
    #pragma unroll
    for (int b = 0; b < 4; ++b)
        dft4p_(x[b], x[4+b], x[8+b], x[12+b], Y[b][0], Y[b][1], Y[b][2], Y[b][3]);
    Y[1][1] = cmul_(Y[1][1],  C1,  S1);
    Y[1][2] = cmul_(Y[1][2],   R,   R);
    Y[1][3] = cmul_(Y[1][3],  S1,  C1);
    Y[2][1] = cmul_(Y[2][1],   R,   R);
    Y[2][2] = make_float2(-Y[2][2].y, Y[2][2].x);
    Y[2][3] = cmul_(Y[2][3],  -R,   R);
    Y[3][1] = cmul_(Y[3][1],  S1,  C1);
    Y[3][2] = cmul_(Y[3][2],  -R,   R);
    Y[3][3] = cmul_(Y[3][3], -C1, -S1);
    #pragma unroll
    for (int c = 0; c < 4; ++c)
        dft4p_(Y[0][c], Y[1][c], Y[2][c], Y[3][c], X[c], X[c+4], X[c+8], X[c+12]);
}

// 8-point DFT, +i convention
__device__ __forceinline__ void fft8p_(const float2* x, float2* X){
    const float R = 0.7071067811865476f;
    float2 Y0[4], Y1[4];
    dft4p_(x[0], x[2], x[4], x[6], Y0[0], Y0[1], Y0[2], Y0[3]);
    dft4p_(x[1], x[3], x[5], x[7], Y1[0], Y1[1], Y1[2], Y1[3]);
    float2 T0 = Y1[0];
    float2 T1 = cmul_(Y1[1],  R, R);
    float2 T2 = make_float2(-Y1[2].y, Y1[2].x);
    float2 T3 = cmul_(Y1[3], -R, R);
    X[0] = cadd_(Y0[0], T0);  X[4] = csub_(Y0[0], T0);
    X[1] = cadd_(Y0[1], T1);  X[5] = csub_(Y0[1], T1);
    X[2] = cadd_(Y0[2], T2);  X[6] = csub_(Y0[2], T2);
    X[3] = cadd_(Y0[3], T3);  X[7] = csub_(Y0[3], T3);
}

// ---------------------------------------------------------------------------
// Tables (float2 indices in T):
//   TW368P @    0 (368)  [n2*16+k1] = e^{+2pi i k1 n2/368}
//   TW640P @  368 (640)  [n2*16+k1] = e^{+2pi i k1 n2/640}
//   TW40P  @ 1008 ( 40)  [m2*8+j1]  = e^{+2pi i j1 m2/40}
//   F23P   @ 1048 (253)  [k2*11+m-1]= (cos,sin)(2pi k2 m/23)
// ---------------------------------------------------------------------------
__global__ void init_tables_kernel(float2* __restrict__ T){
    int i = blockIdx.x*blockDim.x + threadIdx.x;
    if (i >= 1301) return;
    int r, c, modN; int j;
    if      (i <  368){ j = i;        r = j%16; c = j/16; modN = 368; }
    else if (i < 1008){ j = i-368;    r = j%16; c = j/16; modN = 640; }
    else if (i < 1048){ j = i-1008;   r = j%8;  c = j/8;  modN = 40;  }
    else              { j = i-1048;   r = j/11; c = j%11 + 1; modN = 23; }
    int t = (int)(((long long)r * c) % modN);
    if (t > modN/2) t -= modN;
    float ang = (float)(6.283185307179586 * ((double)t / (double)modN));
    float s, co;
    sincosf(ang, &s, &co);
    T[i] = make_float2(co, s);
}

// ---------------------------------------------------------------------------
// K1 (fused kbranch + W-FFT): block = 4 consecutive h rows of one b.
//  Phase 1: stage 6 input rows x 2ch as bf16 (coalesced).
//  Phase 2: SWAPPED-operand MFMA conv3x3(2->32): D[ch][px] comes out
//           transposed, so the px<->ch transpose for the 1x1 conv is done
//           IN REGISTERS with 6 shfl_xor (no LDS round trip, no lgkmcnt(0)
//           fences, iterations independent -> compiler pipelines groups).
//  Phase 3: W-FFT (368 = 16*23) on the 4 in-LDS lines; store Bt transposed.
// ---------------------------------------------------------------------------
__global__ __launch_bounds__(256) void kfftw_kernel(const float* __restrict__ ksp,
                               const float* __restrict__ wk,
                               const float* __restrict__ bk,
                               const float* __restrict__ w1,
                               const float* __restrict__ b1,
                               const float2* __restrict__ TW368P,
                               const float2* __restrict__ F23P,
                               float2* __restrict__ Bt){
    __shared__ unsigned short Sb[4464];     // 6 rows x 2ch x 372
    __shared__ float2 X[FROWS*369];         // fft working set (11,808 B)
    int t = threadIdx.x;
    int blk = blockIdx.x;                   // b*160 + h0/4
    int b  = blk / 160;
    int h0 = (blk - b*160) * FROWS;

    // Phase 1: stage rows h0-1 .. h0+4, both channels, halo col +1
    for (int seg = 0; seg < 12; ++seg){
        int r = seg >> 1, ic = seg & 1;
        int hh = h0 - 1 + r;
        int ok = ((unsigned)hh < 640u);
        const float* base = ksp + ((size_t)(b*2 + ic)*640 + (ok ? hh : 0))*368;
        for (int col = t; col < 372; col += 256){
            int c = col - 1;
            float v = (ok && (unsigned)c < 368u) ? base[c] : 0.f;
            Sb[seg*372 + col] = f2bf(v);
        }
    }

    int lane = t & 63, wave = t >> 6;
    int oc = lane & 15, q = lane >> 4;      // oc: px for gather / outch for MFMA2
    int l = wave;                           // wave owns row h0+l

    int off[8];
    v8s bf0, bf1, b2f;
    #pragma unroll
    for (int j = 0; j < 8; ++j){
        int kk = q*8 + j;
        if (kk < 18){
            int ic = (kk >= 9) ? 1 : 0;
            int tt = kk - ic*9;
            int ty = tt/3, tx = tt - ty*3;
            off[j] = ((ty + l)*2 + ic)*372 + tx;
            bf0[j] = (short)f2bf(wk[oc*18 + kk]);
            bf1[j] = (short)f2bf(wk[(oc+16)*18 + kk]);
        } else {
            off[j] = 0;                     // never read (exec-masked)
            bf0[j] = 0; bf1[j] = 0;
        }
        b2f[j] = (oc < 2) ? (short)f2bf(w1[oc*32 + kk]) : (short)0;
    }
    // conv1 bias now indexed by accumulator row (= output channel 4q+r)
    float bkA[4], bkB[4];
    #pragma unroll
    for (int r = 0; r < 4; ++r){
        bkA[r] = bk[q*4 + r];
        bkB[r] = bk[16 + q*4 + r];
    }
    float biasn = (oc == 1) ? b1[1] : b1[0];
    bool qis0 = (q == 0), qis1 = (q == 1), qis2 = (q == 2);
    bool qhi  = (q & 2) != 0;
    float* Xf = (float*)X;
    __syncthreads();

    // Phase 2: 23 groups of 16 px per wave (row l). No LDS transpose buffer,
    // no full lgkmcnt fences -> iterations overlap.
    for (int g = 0; g < 23; ++g){
        int w0m = g*16 + oc;
        v8s af;
        #pragma unroll
        for (int j = 0; j < 8; ++j){
            short v = 0;
            if (q*8 + j < 18) v = (short)Sb[off[j] + w0m];  // exec-masked read
            af[j] = v;
        }
        // swapped operands: D[row=ch(4q+r)][col=px(oc)], bias folded into C-in
        v4f d0 = {bkA[0], bkA[1], bkA[2], bkA[3]};
        v4f d1 = {bkB[0], bkB[1], bkB[2], bkB[3]};
        d0 = __builtin_amdgcn_mfma_f32_16x16x32_bf16(bf0, af, d0, 0, 0, 0);
        d1 = __builtin_amdgcn_mfma_f32_16x16x32_bf16(bf1, af, d1, 0, 0, 0);
        // leaky + pack: p0 = ch(4q,4q+1), p1 = ch(4q+2,4q+3),
        //               p2 = ch(16+4q,16+4q+1), p3 = ch(16+4q+2,16+4q+3)
        unsigned p0 = cvtpk_(leaky_(d0[0]), leaky_(d0[1]));
        unsigned p1 = cvtpk_(leaky_(d0[2]), leaky_(d0[3]));
        unsigned p2 = cvtpk_(leaky_(d1[0]), leaky_(d1[1]));
        unsigned p3 = cvtpk_(leaky_(d1[2]), leaky_(d1[3]));
        // in-register 16x32 transpose: dest lane (px=oc, q) needs ch[8q..8q+8)
        unsigned vSa = qhi ? p2 : p0, vSb = qhi ? p3 : p1;   // for xor16
        unsigned vTa = qhi ? p0 : p2, vTb = qhi ? p1 : p3;   // for xor32/xor48
        unsigned X16a = __shfl_xor(vSa, 16), X16b = __shfl_xor(vSb, 16);
        unsigned X32a = __shfl_xor(vTa, 32), X32b = __shfl_xor(vTb, 32);
        unsigned X48a = __shfl_xor(vTa, 48), X48b = __shfl_xor(vTb, 48);
        unsigned m0 = qis0 ? p0   : (qis1 ? X48a : (qis2 ? X32a : X16a));
        unsigned m1 = qis0 ? p1   : (qis1 ? X48b : (qis2 ? X32b : X16b));
        unsigned m2 = qis0 ? X16a : (qis1 ? X32a : (qis2 ? X48a : p2));
        unsigned m3 = qis0 ? X16b : (qis1 ? X32b : (qis2 ? X48b : p3));
        union { unsigned u[4]; v8s s; } uu;
        uu.u[0] = m0; uu.u[1] = m1; uu.u[2] = m2; uu.u[3] = m3;
        v4f d2 = {biasn, biasn, biasn, biasn};
        d2 = __builtin_amdgcn_mfma_f32_16x16x32_bf16(uu.s, b2f, d2, 0, 0, 0);
        // d2[r] = outch oc at px = g*16 + q*4 + r; lanes oc<2 write re/im
        if (oc < 2){
            #pragma unroll
            for (int r = 0; r < 4; ++r){
                int px = g*16 + q*4 + r;
                float s = (r & 1) ? -1.f : 1.f;    // (-1)^px (px parity = r)
                Xf[(l*369 + px)*2 + oc] = s * leaky_(d2[r]);
            }
        }
    }
    __syncthreads();

    // Phase 3a: FFT16 over n1, items (l,n2) = 92
    if (t < 92){
        int ll = t & 3, n2 = t >> 2;
        float2 xr[16], Xo[16];
        #pragma unroll
        for (int n1 = 0; n1 < 16; ++n1) xr[n1] = X[ll*369 + 23*n1 + n2];
        fft16p_(xr, Xo);
        const float2* row = TW368P + n2*16;
        #pragma unroll
        for (int k1 = 0; k1 < 16; ++k1)
            X[ll*369 + 23*k1 + n2] = cmulv_(Xo[k1], row[k1]);
    }
    __syncthreads();

    // Phase 3b: DFT23 via pairs; 256 units = (l,k1,quarter)
    {
        int ll = t & 3, k1 = (t >> 2) & 15, qr = t >> 6;   // qr wave-uniform
        const float2* xp = X + ll*369 + 23*k1;
        float2 x0 = xp[0];
        float2 u[11], d[11];
        #pragma unroll
        for (int m = 1; m <= 11; ++m){
            float2 a = xp[m], bb = xp[23-m];
            u[m-1] = cadd_(a, bb);
            d[m-1] = csub_(a, bb);
        }
        __syncthreads();
        int k2beg = qr*6;
        int k2end = (qr == 3) ? 23 : k2beg + 6;
        for (int k2 = k2beg; k2 < k2end; ++k2){
            const float2* row = F23P + k2*11;      // wave-uniform -> s_load
            float re = x0.x, im = x0.y;
            #pragma unroll
            for (int m = 0; m < 11; ++m){
                float c = row[m].x, s = row[m].y;
                re += u[m].x*c - d[m].y*s;
                im += u[m].y*c + d[m].x*s;
            }
            X[ll*369 + k1 + 16*k2] = make_float2(re, im);
        }
    }
    __syncthreads();

    // Phase 3c: transposed store Bt[(b*368+k)*640 + h0 + l]
    const float sc = 0.052129458158616354f;        // 1/sqrt(368)
    for (int i = t; i < FROWS*368; i += 256){
        int k = i >> 2, ll = i & 3;
        float2 v = X[ll*369 + k];
        float s = (k & 1) ? -sc : sc;              // (-1)^k
        Bt[((size_t)(b*368 + k))*640 + h0 + ll] = make_float2(v.x*s, v.y*s);
    }
}

// ---------------------------------------------------------------------------
// K2: H-axis centered IFFT, H = 640 = 16*8*5.  Line-major over Bt[b][w][h];
// output A2[b][w][h] contiguous. Fully coalesced global IO.  736 blocks.
// ---------------------------------------------------------------------------
__global__ __launch_bounds__(256) void fftH_kernel(const float2* __restrict__ Bt,
                                                   const float2* __restrict__ TW640P,
                                                   const float2* __restrict__ TW40P,
                                                   float2* __restrict__ A2){
    __shared__ float2 X[HLINES*HP];       // 20,640 B
    int t = threadIdx.x;
    size_t base = (size_t)blockIdx.x * (HLINES*640);

    for (int i = t; i < HLINES*640; i += 256){
        int l = i / 640, n = i - l*640;
        float2 v = Bt[base + i];
        float s = (n & 1) ? -1.f : 1.f;            // (-1)^n
        X[l*HP + n] = make_float2(v.x*s, v.y*s);
    }
    __syncthreads();

    // stage 1: FFT16 over n1, items (l,n2) = 160
    if (t < 160){
        int l = t & 3, n2 = t >> 2;
        float2 xr[16], Xo[16];
        #pragma unroll
        for (int n1 = 0; n1 < 16; ++n1) xr[n1] = X[l*HP + 40*n1 + n2];
        fft16p_(xr, Xo);
        const float2* row = TW640P + n2*16;
        #pragma unroll
        for (int k1 = 0; k1 < 16; ++k1)
            X[l*HP + 40*k1 + n2] = cmulv_(Xo[k1], row[k1]);
    }
    __syncthreads();

    // stage 2a: FFT8 over m1, items (l,k1,m2) = 320
    for (int it = t; it < 320; it += 256){
        int l = it & 3, k1 = (it >> 2) & 15, m2 = it >> 6;
        float2 xr[8], Xo[8];
        #pragma unroll
        for (int m1 = 0; m1 < 8; ++m1) xr[m1] = X[l*HP + 40*k1 + 5*m1 + m2];
        fft8p_(xr, Xo);
        const float2* row = TW40P + m2*8;
        #pragma unroll
        for (int j1 = 0; j1 < 8; ++j1)
            X[l*HP + 40*k1 + 5*j1 + m2] = cmulv_(Xo[j1], row[j1]);
    }
    __syncthreads();

    // stage 2b: DFT5 over m2 via pairs, items (l,k1,j1) = 512 -> 2/thread
    {
        const float CK1[5] = {1.f,  0.30901699437494745f, -0.8090169943749475f, -0.8090169943749475f,  0.30901699437494745f};
        const float SK1[5] = {0.f,  0.9510565162951535f,   0.5877852522924731f, -0.5877852522924731f, -0.9510565162951535f};
        const float CK2[5] = {1.f, -0.8090169943749475f,   0.30901699437494745f, 0.30901699437494745f, -0.8090169943749475f};
        const float SK2[5] = {0.f,  0.5877852522924731f,  -0.9510565162951535f,  0.9510565162951535f, -0.5877852522924731f};
        int it0 = t, it1 = t + 256;
        int l0 = it0 & 3, k10 = (it0 >> 2) & 15, j10 = it0 >> 6;
        int l1 = it1 & 3, k11 = (it1 >> 2) & 15, j11 = it1 >> 6;
        float2 p0[5], p1[5];
        #pragma unroll
        for (int m2 = 0; m2 < 5; ++m2) p0[m2] = X[l0*HP + 40*k10 + 5*j10 + m2];
        #pragma unroll
        for (int m2 = 0; m2 < 5; ++m2) p1[m2] = X[l1*HP + 40*k11 + 5*j11 + m2];
        __syncthreads();
        float2 u0a = cadd_(p0[1], p0[4]), d0a = csub_(p0[1], p0[4]);
        float2 u0b = cadd_(p0[2], p0[3]), d0b = csub_(p0[2], p0[3]);
        float2 u1a = cadd_(p1[1], p1[4]), d1a = csub_(p1[1], p1[4]);
        float2 u1b = cadd_(p1[2], p1[3]), d1b = csub_(p1[2], p1[3]);
        #pragma unroll
        for (int j2 = 0; j2 < 5; ++j2){
            float c1v = CK1[j2], s1v = SK1[j2], c2v = CK2[j2], s2v = SK2[j2];
            float re0 = p0[0].x + u0a.x*c1v - d0a.y*s1v + u0b.x*c2v - d0b.y*s2v;
            float im0 = p0[0].y + u0a.y*c1v + d0a.x*s1v + u0b.y*c2v + d0b.x*s2v;
            float re1 = p1[0].x + u1a.x*c1v - d1a.y*s1v + u1b.x*c2v - d1b.y*s2v;
            float im1 = p1[0].y + u1a.y*c1v + d1a.x*s1v + u1b.y*c2v + d1b.x*s2v;
            X[l0*HP + k10 + 16*j10 + 128*j2] = make_float2(re0, im0);
            X[l1*HP + k11 + 16*j11 + 128*j2] = make_float2(re1, im1);
        }
    }
    __syncthreads();

    const float sc = 0.03952847075210474f;         // 1/sqrt(640)
    for (int i = t; i < HLINES*640; i += 256){
        int l = i / 640, k = i - l*640;
        float2 v = X[l*HP + k];
        float s = (k & 1) ? -sc : sc;              // (-1)^k
        A2[base + i] = make_float2(v.x*s, v.y*s);
    }
}

// ---------------------------------------------------------------------------
// K3 (fused tail): B-axis FFT8 + magnitude + fp16-emulated conv2(1x1) + leaky
//                  + conv3x3(1->1, pad1) + leaky -> d_out.
// ---------------------------------------------------------------------------
__global__ __launch_bounds__(256) void tail_kernel(const float2* __restrict__ A2,
                                  const float* __restrict__ img,
                                  const float* __restrict__ w2,
                                  const float* __restrict__ b2,
                                  const float* __restrict__ wi,
                                  const float* __restrict__ bi,
                                  float* __restrict__ out){
    __shared__ float Pl[8][TS+2][TS+3];            // pitch 19: 2-way banks
    int t = threadIdx.x;
    int ty0 = (blockIdx.x / 23) * TS;              // 40 tiles over h
    int tx0 = (blockIdx.x % 23) * TS;              // 23 tiles over w

    float w2h0 = __half2float(__float2half(w2[0]));
    float w2h1 = __half2float(__float2half(w2[1]));
    float b2h  = __half2float(__float2half(b2[0]));
    const float sc8 = 0.35355339059327373f;        // 1/sqrt(8)

    // pass 1a: |centered ifft8| from A2, lanes sweep h (coalesced runs)
    for (int idx = t; idx < (TS+2)*(TS+2); idx += 256){
        int hx = idx / (TS+2), hy = idx - hx*(TS+2);
        int hh = ty0 - 1 + hy, ww = tx0 - 1 + hx;
        int hc = min(max(hh, 0), H_-1), wc = min(max(ww, 0), W_-1);
        float2 x[8], Xo[8];
        #pragma unroll
        for (int n = 0; n < 8; ++n){
            float2 v = A2[((size_t)(n*368 + wc))*640 + hc];
            float s = (n & 1) ? -1.f : 1.f;        // (-1)^n
            x[n] = make_float2(v.x*s, v.y*s);
        }
        fft8p_(x, Xo);
        #pragma unroll
        for (int k = 0; k < 8; ++k){
            float s = (k & 1) ? -sc8 : sc8;        // (-1)^k / sqrt(8)
            float yr = Xo[k].x * s, yi = Xo[k].y * s;
            float mag = sqrtf(yr*yr + yi*yi);
            Pl[k][hy][hx] = __half2float(__float2half(mag));
        }
    }
    __syncthreads();

    // pass 1b: conv2 with img, lanes sweep w (coalesced img reads)
    for (int idx = t; idx < (TS+2)*(TS+2); idx += 256){
        int hy = idx / (TS+2), hx = idx - hy*(TS+2);
        int hh = ty0 - 1 + hy, ww = tx0 - 1 + hx;
        bool inb = (hh >= 0) && (hh < H_) && (ww >= 0) && (ww < W_);
        int hc = min(max(hh, 0), H_-1), wc = min(max(ww, 0), W_-1);
        float inbf = inb ? 1.f : 0.f;
        #pragma unroll
        for (int k = 0; k < 8; ++k){
            float g = __half2float(__float2half(img[(size_t)k*HW_ + hc*W_ + wc]));
            float a = Pl[k][hy][hx];
            float o = leaky_(a*w2h0 + g*w2h1 + b2h);
            o = __half2float(__float2half(o));
            Pl[k][hy][hx] = o * inbf;              // zero-pad outside image
        }
    }
    __syncthreads();

    // stage 2: conv3x3 from LDS, 256 spatial px x 8 batch per block
    int sy = t >> 4, sx = t & 15;
    float wv[9];
    #pragma unroll
    for (int q = 0; q < 9; ++q) wv[q] = wi[q];
    float bi0 = bi[0];
    #pragma unroll
    for (int k = 0; k < 8; ++k){
        float acc = bi0;
        #pragma unroll
        for (int dy = 0; dy < 3; ++dy)
            #pragma unroll
            for (int dx = 0; dx < 3; ++dx)
                acc += wv[dy*3+dx] * Pl[k][sy+dy][sx+dx];
        out[((size_t)k*H_ + ty0+sy)*W_ + tx0+sx] = leaky_(acc);
    }
}

// ---------------------------------------------------------------------------
// Workspace layout (bytes):
//   Bt     : float2[NP]    @ 0            (15,073,280)   [b][w][h]
//   A2     : float2[NP]    @ 15,073,280   (15,073,280)   [b][w][h]
//   tables : float2[1301]  @ 30,146,560   (10,408)
// ---------------------------------------------------------------------------
extern "C" void kernel_launch(void* const* d_in, const int* in_sizes, int n_in,
                              void* d_out, int out_size, void* d_ws, size_t ws_size,
                              hipStream_t stream){
    const float* img = (const float*)d_in[0];
    const float* ksp = (const float*)d_in[1];
    const float* wk  = (const float*)d_in[2];
    const float* bk  = (const float*)d_in[3];
    const float* w1  = (const float*)d_in[4];
    const float* b1  = (const float*)d_in[5];
    const float* w2  = (const float*)d_in[6];
    const float* b2  = (const float*)d_in[7];
    const float* wi  = (const float*)d_in[8];
    const float* bi  = (const float*)d_in[9];

    char* ws = (char*)d_ws;
    float2* Bt  = (float2*)(ws + 0);
    float2* A2  = (float2*)(ws + 15073280);
    float2* T   = (float2*)(ws + 30146560);
    float2* TW368P = T + 0;
    float2* TW640P = T + 368;
    float2* TW40P  = T + 1008;
    float2* F23P   = T + 1048;
    float* out  = (float*)d_out;

    init_tables_kernel<<<6, 256, 0, stream>>>(T);

    kfftw_kernel<<<B_*(H_/FROWS), 256, 0, stream>>>(ksp, wk, bk, w1, b1,
                                                    TW368P, F23P, Bt);
    fftH_kernel<<<(B_*W_)/HLINES, 256, 0, stream>>>(Bt, TW640P, TW40P, A2);
    tail_kernel<<<(H_/TS)*(W_/TS), 256, 0, stream>>>(A2, img, w2, b2, wi, bi, out);
}

// Round 2
// 165.422 us; speedup vs baseline: 1.1298x; 1.1298x over previous
//
#include <hip/hip_runtime.h>
#include <hip/hip_fp16.h>
#include <math.h>

// Problem dims
#define B_ 8
#define H_ 640
#define W_ 368
#define HW_ (H_*W_)
#define NP_ (B_*H_*W_)   // 1,884,160

#define FROWS 4          // h-rows per block in fused kbranch+fftW kernel
#define HLINES 4         // (b,w) lines per block in H-axis FFT
#define HP 645           // LDS pitch (float2) for H kernel
#define TS 16            // spatial tile for fused tail kernel

typedef __attribute__((ext_vector_type(8))) short v8s;   // 8 bf16 (4 VGPR)
typedef __attribute__((ext_vector_type(4))) float v4f;   // MFMA acc

__device__ __forceinline__ float leaky_(float x){ return fmaxf(x, 0.01f*x); }

// fp32 -> bf16 round-to-nearest-even
__device__ __forceinline__ unsigned short f2bf(float x){
    unsigned u = __float_as_uint(x);
    u += 0x7FFFu + ((u >> 16) & 1u);
    return (unsigned short)(u >> 16);
}

// DPP row-of-16 sum reduction: after 4 steps every lane of each 16-lane row
// holds the row total.  Pure VALU (v_mov_b32_dpp + v_add_f32) — no LDS.
template<int CTRL>
__device__ __forceinline__ float dppadd_(float v){
    int s = __builtin_amdgcn_update_dpp(0, __float_as_int(v), CTRL, 0xF, 0xF, true);
    return v + __int_as_float(s);
}
__device__ __forceinline__ float rowsum16_(float v){
    v = dppadd_<0x128>(v);   // row_ror:8
    v = dppadd_<0x124>(v);   // row_ror:4
    v = dppadd_<0x4E>(v);    // quad_perm xor2 [2,3,0,1]
    v = dppadd_<0xB1>(v);    // quad_perm xor1 [1,0,3,2]
    return v;
}

__device__ __forceinline__ float2 cadd_(float2 a, float2 b){ return make_float2(a.x+b.x, a.y+b.y); }
__device__ __forceinline__ float2 csub_(float2 a, float2 b){ return make_float2(a.x-b.x, a.y-b.y); }
__device__ __forceinline__ float2 cmul_(float2 a, float c, float s){
    return make_float2(a.x*c - a.y*s, a.x*s + a.y*c);
}
__device__ __forceinline__ float2 cmulv_(float2 a, float2 w){
    return make_float2(a.x*w.x - a.y*w.y, a.x*w.y + a.y*w.x);
}

// DFT4 with +i convention
__device__ __forceinline__ void dft4p_(float2 p0, float2 p1, float2 p2, float2 p3,
                                       float2& z0, float2& z1, float2& z2, float2& z3){
    float2 s0 = cadd_(p0,p2), d0 = csub_(p0,p2);
    float2 s1 = cadd_(p1,p3), d1 = csub_(p1,p3);
    z0 = cadd_(s0,s1);
    z2 = csub_(s0,s1);
    z1 = make_float2(d0.x - d1.y, d0.y + d1.x);
    z3 = make_float2(d0.x + d1.y, d0.y - d1.x);
}

// 16-point DFT, +i convention
__device__ __forceinline__ void fft16p_(const float2* x, float2* X){
    const float C1 = 0.9238795325112867f, S1 = 0.3826834323650898f;
    const float R  = 0.7071067811865476f;
    float2 Y[4][4];
    #pragma unroll
    for (int b = 0; b < 4; ++b)
        dft4p_(x[b], x[4+b], x[8+b], x[12+b], Y[b][0], Y[b][1], Y[b][2], Y[b][3]);
    Y[1][1] = cmul_(Y[1][1],  C1,  S1);
    Y[1][2] = cmul_(Y[1][2],   R,   R);
    Y[1][3] = cmul_(Y[1][3],  S1,  C1);
    Y[2][1] = cmul_(Y[2][1],   R,   R);
    Y[2][2] = make_float2(-Y[2][2].y, Y[2][2].x);
    Y[2][3] = cmul_(Y[2][3],  -R,   R);
    Y[3][1] = cmul_(Y[3][1],  S1,  C1);
    Y[3][2] = cmul_(Y[3][2],  -R,   R);
    Y[3][3] = cmul_(Y[3][3], -C1, -S1);
    #pragma unroll
    for (int c = 0; c < 4; ++c)
        dft4p_(Y[0][c], Y[1][c], Y[2][c], Y[3][c], X[c], X[c+4], X[c+8], X[c+12]);
}

// 8-point DFT, +i convention
__device__ __forceinline__ void fft8p_(const float2* x, float2* X){
    const float R = 0.7071067811865476f;
    float2 Y0[4], Y1[4];
    dft4p_(x[0], x[2], x[4], x[6], Y0[0], Y0[1], Y0[2], Y0[3]);
    dft4p_(x[1], x[3], x[5], x[7], Y1[0], Y1[1], Y1[2], Y1[3]);
    float2 T0 = Y1[0];
    float2 T1 = cmul_(Y1[1],  R, R);
    float2 T2 = make_float2(-Y1[2].y, Y1[2].x);
    float2 T3 = cmul_(Y1[3], -R, R);
    X[0] = cadd_(Y0[0], T0);  X[4] = csub_(Y0[0], T0);
    X[1] = cadd_(Y0[1], T1);  X[5] = csub_(Y0[1], T1);
    X[2] = cadd_(Y0[2], T2);  X[6] = csub_(Y0[2], T2);
    X[3] = cadd_(Y0[3], T3);  X[7] = csub_(Y0[3], T3);
}

// ---------------------------------------------------------------------------
// Tables (float2 indices in T):
//   TW368P @    0 (368)  [n2*16+k1] = e^{+2pi i k1 n2/368}
//   TW640P @  368 (640)  [n2*16+k1] = e^{+2pi i k1 n2/640}
//   TW40P  @ 1008 ( 40)  [m2*8+j1]  = e^{+2pi i j1 m2/40}
//   F23P   @ 1048 (253)  [k2*11+m-1]= (cos,sin)(2pi k2 m/23)
// ---------------------------------------------------------------------------
__global__ void init_tables_kernel(float2* __restrict__ T){
    int i = blockIdx.x*blockDim.x + threadIdx.x;
    if (i >= 1301) return;
    int r, c, modN; int j;
    if      (i <  368){ j = i;        r = j%16; c = j/16; modN = 368; }
    else if (i < 1008){ j = i-368;    r = j%16; c = j/16; modN = 640; }
    else if (i < 1048){ j = i-1008;   r = j%8;  c = j/8;  modN = 40;  }
    else              { j = i-1048;   r = j/11; c = j%11 + 1; modN = 23; }
    int t = (int)(((long long)r * c) % modN);
    if (t > modN/2) t -= modN;
    float ang = (float)(6.283185307179586 * ((double)t / (double)modN));
    float s, co;
    sincosf(ang, &s, &co);
    T[i] = make_float2(co, s);
}

// ---------------------------------------------------------------------------
// K1 (fused kbranch + W-FFT): block = 4 consecutive h rows of one b.
//  Phase 1: stage 6 input rows x 2ch as bf16 (coalesced), zero pad region.
//  Phase 2: MFMA conv3x3(2->32)+leaky.  conv1 (32->2, 1x1) is a 16-lane DPP
//           row reduction in f32 — no LDS transpose buffer, no lgkmcnt
//           fences, no second MFMA.  Iterations fully independent.
//  Phase 3: W-FFT (368 = 16*23) on the 4 in-LDS lines; store Bt transposed.
// ---------------------------------------------------------------------------
__global__ __launch_bounds__(256) void kfftw_kernel(const float* __restrict__ ksp,
                               const float* __restrict__ wk,
                               const float* __restrict__ bk,
                               const float* __restrict__ w1,
                               const float* __restrict__ b1,
                               const float2* __restrict__ TW368P,
                               const float2* __restrict__ F23P,
                               float2* __restrict__ Bt){
    __shared__ unsigned short Sb[4836];     // 6 rows x 2ch x 372 + zero region
    __shared__ float2 X[FROWS*369];         // fft working set (11,808 B)
    int t = threadIdx.x;
    int blk = blockIdx.x;                   // b*160 + h0/4
    int b  = blk / 160;
    int h0 = (blk - b*160) * FROWS;

    // Phase 1: stage rows h0-1 .. h0+4, both channels, halo col +1
    for (int seg = 0; seg < 12; ++seg){
        int r = seg >> 1, ic = seg & 1;
        int hh = h0 - 1 + r;
        int ok = ((unsigned)hh < 640u);
        const float* base = ksp + ((size_t)(b*2 + ic)*640 + (ok ? hh : 0))*368;
        for (int col = t; col < 372; col += 256){
            int c = col - 1;
            float v = (ok && (unsigned)c < 368u) ? base[c] : 0.f;
            Sb[seg*372 + col] = f2bf(v);
        }
    }
    for (int i = t; i < 372; i += 256) Sb[4464 + i] = 0;   // zero pad for k>=18

    int lane = t & 63, wave = t >> 6;
    int oc = lane & 15, q = lane >> 4;
    int l = wave;                           // wave owns row h0+l

    int off[8];
    v8s bf0, bf1;
    #pragma unroll
    for (int j = 0; j < 8; ++j){
        int kk = q*8 + j;
        if (kk < 18){
            int ic = (kk >= 9) ? 1 : 0;
            int tt = kk - ic*9;
            int ty = tt/3, tx = tt - ty*3;
            off[j] = ((ty + l)*2 + ic)*372 + tx;
            bf0[j] = (short)f2bf(wk[oc*18 + kk]);
            bf1[j] = (short)f2bf(wk[(oc+16)*18 + kk]);
        } else {
            off[j] = 4464;                  // zeroed region (uniform read)
            bf0[j] = 0; bf1[j] = 0;
        }
    }
    float bk0 = bk[oc], bk1 = bk[oc+16];
    // conv1 weights for this lane's two channels (oc, oc+16), both outputs
    float w10a = w1[oc],      w10b = w1[16+oc];
    float w11a = w1[32+oc],   w11b = w1[48+oc];
    float b10 = b1[0], b11 = b1[1];
    __syncthreads();

    // Phase 2: 23 groups of 16 px per wave (row l).  Chain per group:
    // gather(ds_read_u16) -> MFMA x2 -> leaky/fma -> 4-step DPP rowsum ->
    // (lane oc==0) write X.  No fences; groups overlap.
    for (int g = 0; g < 23; ++g){
        int w0m = g*16 + oc;
        v8s af;
        #pragma unroll
        for (int j = 0; j < 8; ++j) af[j] = (short)Sb[off[j] + w0m];
        v4f d0 = {bk0, bk0, bk0, bk0};      // bias folded into C-in
        v4f d1 = {bk1, bk1, bk1, bk1};
        d0 = __builtin_amdgcn_mfma_f32_16x16x32_bf16(af, bf0, d0, 0, 0, 0);
        d1 = __builtin_amdgcn_mfma_f32_16x16x32_bf16(af, bf1, d1, 0, 0, 0);
        // conv1 partials in f32: lane holds ch oc (d0) and oc+16 (d1) for
        // pixels px = g*16 + q*4 + r
        float s0[4], s1[4];
        #pragma unroll
        for (int r = 0; r < 4; ++r){
            float y0 = leaky_(d0[r]), y1 = leaky_(d1[r]);
            s0[r] = y0*w10a + y1*w10b;      // -> out channel 0 (re)
            s1[r] = y0*w11a + y1*w11b;      // -> out channel 1 (im)
        }
        #pragma unroll
        for (int r = 0; r < 4; ++r){
            s0[r] = rowsum16_(s0[r]);
            s1[r] = rowsum16_(s1[r]);
        }
        if (oc == 0){
            #pragma unroll
            for (int r = 0; r < 4; ++r){
                int px = g*16 + q*4 + r;
                float sg = (r & 1) ? -1.f : 1.f;       // (-1)^px
                float o0 = leaky_(s0[r] + b10);
                float o1 = leaky_(s1[r] + b11);
                X[l*369 + px] = make_float2(sg*o0, sg*o1);
            }
        }
    }
    __syncthreads();

    // Phase 3a: FFT16 over n1, items (l,n2) = 92
    if (t < 92){
        int ll = t & 3, n2 = t >> 2;
        float2 xr[16], Xo[16];
        #pragma unroll
        for (int n1 = 0; n1 < 16; ++n1) xr[n1] = X[ll*369 + 23*n1 + n2];
        fft16p_(xr, Xo);
        const float2* row = TW368P + n2*16;
        #pragma unroll
        for (int k1 = 0; k1 < 16; ++k1)
            X[ll*369 + 23*k1 + n2] = cmulv_(Xo[k1], row[k1]);
    }
    __syncthreads();

    // Phase 3b: DFT23 via pairs; 256 units = (l,k1,quarter)
    {
        int ll = t & 3, k1 = (t >> 2) & 15, qr = t >> 6;   // qr wave-uniform
        const float2* xp = X + ll*369 + 23*k1;
        float2 x0 = xp[0];
        float2 u[11], d[11];
        #pragma unroll
        for (int m = 1; m <= 11; ++m){
            float2 a = xp[m], bb = xp[23-m];
            u[m-1] = cadd_(a, bb);
            d[m-1] = csub_(a, bb);
        }
        __syncthreads();
        int k2beg = qr*6;
        int k2end = (qr == 3) ? 23 : k2beg + 6;
        for (int k2 = k2beg; k2 < k2end; ++k2){
            const float2* row = F23P + k2*11;      // wave-uniform -> s_load
            float re = x0.x, im = x0.y;
            #pragma unroll
            for (int m = 0; m < 11; ++m){
                float c = row[m].x, s = row[m].y;
                re += u[m].x*c - d[m].y*s;
                im += u[m].y*c + d[m].x*s;
            }
            X[ll*369 + k1 + 16*k2] = make_float2(re, im);
        }
    }
    __syncthreads();

    // Phase 3c: transposed store Bt[(b*368+k)*640 + h0 + l]
    const float sc = 0.052129458158616354f;        // 1/sqrt(368)
    for (int i = t; i < FROWS*368; i += 256){
        int k = i >> 2, ll = i & 3;
        float2 v = X[ll*369 + k];
        float s = (k & 1) ? -sc : sc;              // (-1)^k
        Bt[((size_t)(b*368 + k))*640 + h0 + ll] = make_float2(v.x*s, v.y*s);
    }
}

// ---------------------------------------------------------------------------
// K2: H-axis centered IFFT, H = 640 = 16*8*5.  Line-major over Bt[b][w][h];
// output A2[b][w][h] contiguous. Fully coalesced global IO.  736 blocks.
// ---------------------------------------------------------------------------
__global__ __launch_bounds__(256) void fftH_kernel(const float2* __restrict__ Bt,
                                                   const float2* __restrict__ TW640P,
                                                   const float2* __restrict__ TW40P,
                                                   float2* __restrict__ A2){
    __shared__ float2 X[HLINES*HP];       // 20,640 B
    int t = threadIdx.x;
    size_t base = (size_t)blockIdx.x * (HLINES*640);

    for (int i = t; i < HLINES*640; i += 256){
        int l = i / 640, n = i - l*640;
        float2 v = Bt[base + i];
        float s = (n & 1) ? -1.f : 1.f;            // (-1)^n
        X[l*HP + n] = make_float2(v.x*s, v.y*s);
    }
    __syncthreads();

    // stage 1: FFT16 over n1, items (l,n2) = 160
    if (t < 160){
        int l = t & 3, n2 = t >> 2;
        float2 xr[16], Xo[16];
        #pragma unroll
        for (int n1 = 0; n1 < 16; ++n1) xr[n1] = X[l*HP + 40*n1 + n2];
        fft16p_(xr, Xo);
        const float2* row = TW640P + n2*16;
        #pragma unroll
        for (int k1 = 0; k1 < 16; ++k1)
            X[l*HP + 40*k1 + n2] = cmulv_(Xo[k1], row[k1]);
    }
    __syncthreads();

    // stage 2a: FFT8 over m1, items (l,k1,m2) = 320
    for (int it = t; it < 320; it += 256){
        int l = it & 3, k1 = (it >> 2) & 15, m2 = it >> 6;
        float2 xr[8], Xo[8];
        #pragma unroll
        for (int m1 = 0; m1 < 8; ++m1) xr[m1] = X[l*HP + 40*k1 + 5*m1 + m2];
        fft8p_(xr, Xo);
        const float2* row = TW40P + m2*8;
        #pragma unroll
        for (int j1 = 0; j1 < 8; ++j1)
            X[l*HP + 40*k1 + 5*j1 + m2] = cmulv_(Xo[j1], row[j1]);
    }
    __syncthreads();

    // stage 2b: DFT5 over m2 via pairs, items (l,k1,j1) = 512 -> 2/thread
    {
        const float CK1[5] = {1.f,  0.30901699437494745f, -0.8090169943749475f, -0.8090169943749475f,  0.30901699437494745f};
        const float SK1[5] = {0.f,  0.9510565162951535f,   0.5877852522924731f, -0.5877852522924731f, -0.9510565162951535f};
        const float CK2[5] = {1.f, -0.8090169943749475f,   0.30901699437494745f, 0.30901699437494745f, -0.8090169943749475f};
        const float SK2[5] = {0.f,  0.5877852522924731f,  -0.9510565162951535f,  0.9510565162951535f, -0.5877852522924731f};
        int it0 = t, it1 = t + 256;
        int l0 = it0 & 3, k10 = (it0 >> 2) & 15, j10 = it0 >> 6;
        int l1 = it1 & 3, k11 = (it1 >> 2) & 15, j11 = it1 >> 6;
        float2 p0[5], p1[5];
        #pragma unroll
        for (int m2 = 0; m2 < 5; ++m2) p0[m2] = X[l0*HP + 40*k10 + 5*j10 + m2];
        #pragma unroll
        for (int m2 = 0; m2 < 5; ++m2) p1[m2] = X[l1*HP + 40*k11 + 5*j11 + m2];
        __syncthreads();
        float2 u0a = cadd_(p0[1], p0[4]), d0a = csub_(p0[1], p0[4]);
        float2 u0b = cadd_(p0[2], p0[3]), d0b = csub_(p0[2], p0[3]);
        float2 u1a = cadd_(p1[1], p1[4]), d1a = csub_(p1[1], p1[4]);
        float2 u1b = cadd_(p1[2], p1[3]), d1b = csub_(p1[2], p1[3]);
        #pragma unroll
        for (int j2 = 0; j2 < 5; ++j2){
            float c1v = CK1[j2], s1v = SK1[j2], c2v = CK2[j2], s2v = SK2[j2];
            float re0 = p0[0].x + u0a.x*c1v - d0a.y*s1v + u0b.x*c2v - d0b.y*s2v;
            float im0 = p0[0].y + u0a.y*c1v + d0a.x*s1v + u0b.y*c2v + d0b.x*s2v;
            float re1 = p1[0].x + u1a.x*c1v - d1a.y*s1v + u1b.x*c2v - d1b.y*s2v;
            float im1 = p1[0].y + u1a.y*c1v + d1a.x*s1v + u1b.y*c2v + d1b.x*s2v;
            X[l0*HP + k10 + 16*j10 + 128*j2] = make_float2(re0, im0);
            X[l1*HP + k11 + 16*j11 + 128*j2] = make_float2(re1, im1);
        }
    }
    __syncthreads();

    const float sc = 0.03952847075210474f;         // 1/sqrt(640)
    for (int i = t; i < HLINES*640; i += 256){
        int l = i / 640, k = i - l*640;
        float2 v = X[l*HP + k];
        float s = (k & 1) ? -sc : sc;              // (-1)^k
        A2[base + i] = make_float2(v.x*s, v.y*s);
    }
}

// ---------------------------------------------------------------------------
// K3 (fused tail): B-axis FFT8 + magnitude + fp16-emulated conv2(1x1) + leaky
//                  + conv3x3(1->1, pad1) + leaky -> d_out.
// ---------------------------------------------------------------------------
__global__ __launch_bounds__(256) void tail_kernel(const float2* __restrict__ A2,
                                  const float* __restrict__ img,
                                  const float* __restrict__ w2,
                                  const float* __restrict__ b2,
                                  const float* __restrict__ wi,
                                  const float* __restrict__ bi,
                                  float* __restrict__ out){
    __shared__ float Pl[8][TS+2][TS+3];            // pitch 19: 2-way banks
    int t = threadIdx.x;
    int ty0 = (blockIdx.x / 23) * TS;              // 40 tiles over h
    int tx0 = (blockIdx.x % 23) * TS;              // 23 tiles over w

    float w2h0 = __half2float(__float2half(w2[0]));
    float w2h1 = __half2float(__float2half(w2[1]));
    float b2h  = __half2float(__float2half(b2[0]));
    const float sc8 = 0.35355339059327373f;        // 1/sqrt(8)

    // pass 1a: |centered ifft8| from A2, lanes sweep h (coalesced runs)
    for (int idx = t; idx < (TS+2)*(TS+2); idx += 256){
        int hx = idx / (TS+2), hy = idx - hx*(TS+2);
        int hh = ty0 - 1 + hy, ww = tx0 - 1 + hx;
        int hc = min(max(hh, 0), H_-1), wc = min(max(ww, 0), W_-1);
        float2 x[8], Xo[8];
        #pragma unroll
        for (int n = 0; n < 8; ++n){
            float2 v = A2[((size_t)(n*368 + wc))*640 + hc];
            float s = (n & 1) ? -1.f : 1.f;        // (-1)^n
            x[n] = make_float2(v.x*s, v.y*s);
        }
        fft8p_(x, Xo);
        #pragma unroll
        for (int k = 0; k < 8; ++k){
            float s = (k & 1) ? -sc8 : sc8;        // (-1)^k / sqrt(8)
            float yr = Xo[k].x * s, yi = Xo[k].y * s;
            float mag = sqrtf(yr*yr + yi*yi);
            Pl[k][hy][hx] = __half2float(__float2half(mag));
        }
    }
    __syncthreads();

    // pass 1b: conv2 with img, lanes sweep w (coalesced img reads)
    for (int idx = t; idx < (TS+2)*(TS+2); idx += 256){
        int hy = idx / (TS+2), hx = idx - hy*(TS+2);
        int hh = ty0 - 1 + hy, ww = tx0 - 1 + hx;
        bool inb = (hh >= 0) && (hh < H_) && (ww >= 0) && (ww < W_);
        int hc = min(max(hh, 0), H_-1), wc = min(max(ww, 0), W_-1);
        float inbf = inb ? 1.f : 0.f;
        #pragma unroll
        for (int k = 0; k < 8; ++k){
            float g = __half2float(__float2half(img[(size_t)k*HW_ + hc*W_ + wc]));
            float a = Pl[k][hy][hx];
            float o = leaky_(a*w2h0 + g*w2h1 + b2h);
            o = __half2float(__float2half(o));
            Pl[k][hy][hx] = o * inbf;              // zero-pad outside image
        }
    }
    __syncthreads();

    // stage 2: conv3x3 from LDS, 256 spatial px x 8 batch per block
    int sy = t >> 4, sx = t & 15;
    float wv[9];
    #pragma unroll
    for (int q = 0; q < 9; ++q) wv[q] = wi[q];
    float bi0 = bi[0];
    #pragma unroll
    for (int k = 0; k < 8; ++k){
        float acc = bi0;
        #pragma unroll
        for (int dy = 0; dy < 3; ++dy)
            #pragma unroll
            for (int dx = 0; dx < 3; ++dx)
                acc += wv[dy*3+dx] * Pl[k][sy+dy][sx+dx];
        out[((size_t)k*H_ + ty0+sy)*W_ + tx0+sx] = leaky_(acc);
    }
}

// ---------------------------------------------------------------------------
// Workspace layout (bytes):
//   Bt     : float2[NP]    @ 0            (15,073,280)   [b][w][h]
//   A2     : float2[NP]    @ 15,073,280   (15,073,280)   [b][w][h]
//   tables : float2[1301]  @ 30,146,560   (10,408)
// ---------------------------------------------------------------------------
extern "C" void kernel_launch(void* const* d_in, const int* in_sizes, int n_in,
                              void* d_out, int out_size, void* d_ws, size_t ws_size,
                              hipStream_t stream){
    const float* img = (const float*)d_in[0];
    const float* ksp = (const float*)d_in[1];
    const float* wk  = (const float*)d_in[2];
    const float* bk  = (const float*)d_in[3];
    const float* w1  = (const float*)d_in[4];
    const float* b1  = (const float*)d_in[5];
    const float* w2  = (const float*)d_in[6];
    const float* b2  = (const float*)d_in[7];
    const float* wi  = (const float*)d_in[8];
    const float* bi  = (const float*)d_in[9];

    char* ws = (char*)d_ws;
    float2* Bt  = (float2*)(ws + 0);
    float2* A2  = (float2*)(ws + 15073280);
    float2* T   = (float2*)(ws + 30146560);
    float2* TW368P = T + 0;
    float2* TW640P = T + 368;
    float2* TW40P  = T + 1008;
    float2* F23P   = T + 1048;
    float* out  = (float*)d_out;

    init_tables_kernel<<<6, 256, 0, stream>>>(T);

    kfftw_kernel<<<B_*(H_/FROWS), 256, 0, stream>>>(ksp, wk, bk, w1, b1,
                                                    TW368P, F23P, Bt);
    fftH_kernel<<<(B_*W_)/HLINES, 256, 0, stream>>>(Bt, TW640P, TW40P, A2);
    tail_kernel<<<(H_/TS)*(W_/TS), 256, 0, stream>>>(A2, img, w2, b2, wi, bi, out);
}

// Round 3
// 155.607 us; speedup vs baseline: 1.2011x; 1.0631x over previous
//
#include <hip/hip_runtime.h>
#include <hip/hip_fp16.h>
#include <math.h>

// Problem dims
#define B_ 8
#define H_ 640
#define W_ 368
#define HW_ (H_*W_)
#define NP_ (B_*H_*W_)   // 1,884,160

#define FROWS 4          // h-rows per block in fused kbranch+fftW kernel
#define HLINES 4         // (b,w) lines per block in H-axis FFT
#define HP 645           // LDS pitch (float2) for H kernel
#define TS 16            // spatial tile for fused tail kernel

typedef __attribute__((ext_vector_type(8))) short v8s;    // 8 bf16 (4 VGPR)
typedef __attribute__((ext_vector_type(4))) float v4f;    // MFMA acc (16x16)
typedef __attribute__((ext_vector_type(16))) float v16f;  // MFMA acc (32x32)

__device__ __forceinline__ float leaky_(float x){ return fmaxf(x, 0.01f*x); }

// fp32 -> bf16 round-to-nearest-even
__device__ __forceinline__ unsigned short f2bf(float x){
    unsigned u = __float_as_uint(x);
    u += 0x7FFFu + ((u >> 16) & 1u);
    return (unsigned short)(u >> 16);
}

__device__ __forceinline__ float2 cadd_(float2 a, float2 b){ return make_float2(a.x+b.x, a.y+b.y); }
__device__ __forceinline__ float2 csub_(float2 a, float2 b){ return make_float2(a.x-b.x, a.y-b.y); }
__device__ __forceinline__ float2 cmul_(float2 a, float c, float s){
    return make_float2(a.x*c - a.y*s, a.x*s + a.y*c);
}
__device__ __forceinline__ float2 cmulv_(float2 a, float2 w){
    return make_float2(a.x*w.x - a.y*w.y, a.x*w.y + a.y*w.x);
}

// DFT4 with +i convention
__device__ __forceinline__ void dft4p_(float2 p0, float2 p1, float2 p2, float2 p3,
                                       float2& z0, float2& z1, float2& z2, float2& z3){
    float2 s0 = cadd_(p0,p2), d0 = csub_(p0,p2);
    float2 s1 = cadd_(p1,p3), d1 = csub_(p1,p3);
    z0 = cadd_(s0,s1);
    z2 = csub_(s0,s1);
    z1 = make_float2(d0.x - d1.y, d0.y + d1.x);
    z3 = make_float2(d0.x + d1.y, d0.y - d1.x);
}

// 16-point DFT, +i convention
__device__ __forceinline__ void fft16p_(const float2* x, float2* X){
    const float C1 = 0.9238795325112867f, S1 = 0.3826834323650898f;
    const float R  = 0.7071067811865476f;
    float2 Y[4][4];
    #pragma unroll
    for (int b = 0; b < 4; ++b)
        dft4p_(x[b], x[4+b], x[8+b], x[12+b], Y[b][0], Y[b][1], Y[b][2], Y[b][3]);
    Y[1][1] = cmul_(Y[1][1],  C1,  S1);
    Y[1][2] = cmul_(Y[1][2],   R,   R);
    Y[1][3] = cmul_(Y[1][3],  S1,  C1);
    Y[2][1] = cmul_(Y[2][1],   R,   R);
    Y[2][2] = make_float2(-Y[2][2].y, Y[2][2].x);
    Y[2][3] = cmul_(Y[2][3],  -R,   R);
    Y[3][1] = cmul_(Y[3][1],  S1,  C1);
    Y[3][2] = cmul_(Y[3][2],  -R,   R);
    Y[3][3] = cmul_(Y[3][3], -C1, -S1);
    #pragma unroll
    for (int c = 0; c < 4; ++c)
        dft4p_(Y[0][c], Y[1][c], Y[2][c], Y[3][c], X[c], X[c+4], X[c+8], X[c+12]);
}

// 8-point DFT, +i convention
__device__ __forceinline__ void fft8p_(const float2* x, float2* X){
    const float R = 0.7071067811865476f;
    float2 Y0[4], Y1[4];
    dft4p_(x[0], x[2], x[4], x[6], Y0[0], Y0[1], Y0[2], Y0[3]);
    dft4p_(x[1], x[3], x[5], x[7], Y1[0], Y1[1], Y1[2], Y1[3]);
    float2 T0 = Y1[0];
    float2 T1 = cmul_(Y1[1],  R, R);
    float2 T2 = make_float2(-Y1[2].y, Y1[2].x);
    float2 T3 = cmul_(Y1[3], -R, R);
    X[0] = cadd_(Y0[0], T0);  X[4] = csub_(Y0[0], T0);
    X[1] = cadd_(Y0[1], T1);  X[5] = csub_(Y0[1], T1);
    X[2] = cadd_(Y0[2], T2);  X[6] = csub_(Y0[2], T2);
    X[3] = cadd_(Y0[3], T3);  X[7] = csub_(Y0[3], T3);
}

// ---------------------------------------------------------------------------
// Tables (float2 indices in T):
//   TW368P @    0 (368)  [n2*16+k1] = e^{+2pi i k1 n2/368}
//   TW640P @  368 (640)  [n2*16+k1] = e^{+2pi i k1 n2/640}
//   TW40P  @ 1008 ( 40)  [m2*8+j1]  = e^{+2pi i j1 m2/40}
//   F23P   @ 1048 (253)  [k2*11+m-1]= (cos,sin)(2pi k2 m/23)
// ---------------------------------------------------------------------------
__global__ void init_tables_kernel(float2* __restrict__ T){
    int i = blockIdx.x*blockDim.x + threadIdx.x;
    if (i >= 1301) return;
    int r, c, modN; int j;
    if      (i <  368){ j = i;        r = j%16; c = j/16; modN = 368; }
    else if (i < 1008){ j = i-368;    r = j%16; c = j/16; modN = 640; }
    else if (i < 1048){ j = i-1008;   r = j%8;  c = j/8;  modN = 40;  }
    else              { j = i-1048;   r = j/11; c = j%11 + 1; modN = 23; }
    int t = (int)(((long long)r * c) % modN);
    if (t > modN/2) t -= modN;
    float ang = (float)(6.283185307179586 * ((double)t / (double)modN));
    float s, co;
    sincosf(ang, &s, &co);
    T[i] = make_float2(co, s);
}

// ---------------------------------------------------------------------------
// K1 (fused kbranch + W-FFT): block = 4 consecutive h rows of one b.
//  Phase 1: stage 6 input rows x 2ch as bf16 (coalesced), zero pad region.
//  Phase 2: 32x32x16 MFMA, operands swapped: D[ch][px] with px = lane&31.
//           Each lane holds 16 of 32 channels for ONE pixel -> conv1 is
//           16 in-lane FMA pairs + one shfl_xor(32) per output. Taps 16,17
//           and the bk bias (constant-1 tap) go through a 2nd small MFMA.
//  Phase 3: W-FFT (368 = 16*23) on the 4 in-LDS lines; store Bt transposed.
// ---------------------------------------------------------------------------
__global__ __launch_bounds__(256) void kfftw_kernel(const float* __restrict__ ksp,
                               const float* __restrict__ wk,
                               const float* __restrict__ bk,
                               const float* __restrict__ w1,
                               const float* __restrict__ b1,
                               const float2* __restrict__ TW368P,
                               const float2* __restrict__ F23P,
                               float2* __restrict__ Bt){
    __shared__ unsigned short Sb[4836];     // 6 rows x 2ch x 372 + zero region
    __shared__ float2 X[FROWS*369];         // fft working set (11,808 B)
    int t = threadIdx.x;
    int blk = blockIdx.x;                   // b*160 + h0/4
    int b  = blk / 160;
    int h0 = (blk - b*160) * FROWS;

    // Phase 1: stage rows h0-1 .. h0+4, both channels, halo col +1
    for (int seg = 0; seg < 12; ++seg){
        int r = seg >> 1, ic = seg & 1;
        int hh = h0 - 1 + r;
        int ok = ((unsigned)hh < 640u);
        const float* base = ksp + ((size_t)(b*2 + ic)*640 + (ok ? hh : 0))*368;
        for (int col = t; col < 372; col += 256){
            int c = col - 1;
            float v = (ok && (unsigned)c < 368u) ? base[c] : 0.f;
            Sb[seg*372 + col] = f2bf(v);
        }
    }
    for (int i = t; i < 372; i += 256) Sb[4464 + i] = 0;   // zero tail (OOB px)

    int lane = t & 63, wave = t >> 6;
    int ch = lane & 31, h = lane >> 5;      // ch: channel (A row) & pixel (B col)
    int l = wave;                           // wave owns row h0+l

    // A1 = wk[ch][taps 8h..8h+7]; offsets for B gather (same tap order)
    int offB[8];
    v8s a1, a2;
    #pragma unroll
    for (int j = 0; j < 8; ++j){
        int kk = 8*h + j;
        int ic = (kk >= 9) ? 1 : 0;
        int tt = kk - ic*9;
        int ty = tt/3, tx = tt - ty*3;
        offB[j] = ((ty + l)*2 + ic)*372 + tx;
        a1[j] = (short)f2bf(wk[ch*18 + kk]);
        a2[j] = 0;
    }
    if (h == 0){
        a2[0] = (short)f2bf(wk[ch*18 + 16]);   // tap 16 (ic1,ty2,tx1)
        a2[1] = (short)f2bf(wk[ch*18 + 17]);   // tap 17 (ic1,ty2,tx2)
        a2[2] = (short)f2bf(bk[ch]);           // bias as constant-1 tap
    }
    const int off16 = ((2 + l)*2 + 1)*372 + 1;
    const int off17 = off16 + 1;

    // conv1 weights per accumulator reg: row(r,h) = (r&3) + 8*(r>>2) + 4*h
    float wp0[16], wp1[16];
    #pragma unroll
    for (int r = 0; r < 16; ++r){
        int row = (r & 3) + 8*(r >> 2) + 4*h;
        wp0[r] = w1[row];
        wp1[r] = w1[32 + row];
    }
    float b10 = b1[0], b11 = b1[1];
    float sgn = (ch & 1) ? -1.f : 1.f;      // (-1)^px, px parity = ch parity
    __syncthreads();

    // Phase 2: 12 groups of 32 px per wave (row l).
    for (int g = 0; g < 12; ++g){
        int px = g*32 + ch;
        v8s bv;
        #pragma unroll
        for (int j = 0; j < 8; ++j) bv[j] = (short)Sb[offB[j] + px];
        v16f d = {0.f,0.f,0.f,0.f,0.f,0.f,0.f,0.f,0.f,0.f,0.f,0.f,0.f,0.f,0.f,0.f};
        d = __builtin_amdgcn_mfma_f32_32x32x16_bf16(a1, bv, d, 0, 0, 0);
        v8s b2v = {0,0,0,0,0,0,0,0};
        b2v[0] = (short)Sb[off16 + px];
        b2v[1] = (short)Sb[off17 + px];
        b2v[2] = (short)0x3F80;             // bf16(1.0) for the bias tap
        d = __builtin_amdgcn_mfma_f32_32x32x16_bf16(a2, b2v, d, 0, 0, 0);
        // conv1: 16 in-lane channels, then combine halves via xor-32
        float sx = 0.f, sy = 0.f;
        #pragma unroll
        for (int r = 0; r < 16; ++r){
            float y = leaky_(d[r]);
            sx = fmaf(y, wp0[r], sx);
            sy = fmaf(y, wp1[r], sy);
        }
        sx += __shfl_xor(sx, 32);
        sy += __shfl_xor(sy, 32);
        if (h == 0 && px < 368){
            float o0 = leaky_(sx + b10);
            float o1 = leaky_(sy + b11);
            X[l*369 + px] = make_float2(sgn*o0, sgn*o1);
        }
    }
    __syncthreads();

    // Phase 3a: FFT16 over n1, items (l,n2) = 92
    if (t < 92){
        int ll = t & 3, n2 = t >> 2;
        float2 xr[16], Xo[16];
        #pragma unroll
        for (int n1 = 0; n1 < 16; ++n1) xr[n1] = X[ll*369 + 23*n1 + n2];
        fft16p_(xr, Xo);
        const float2* row = TW368P + n2*16;
        #pragma unroll
        for (int k1 = 0; k1 < 16; ++k1)
            X[ll*369 + 23*k1 + n2] = cmulv_(Xo[k1], row[k1]);
    }
    __syncthreads();

    // Phase 3b: DFT23 via pairs; 256 units = (l,k1,quarter)
    {
        int ll = t & 3, k1 = (t >> 2) & 15, qr = t >> 6;   // qr wave-uniform
        const float2* xp = X + ll*369 + 23*k1;
        float2 x0 = xp[0];
        float2 u[11], d[11];
        #pragma unroll
        for (int m = 1; m <= 11; ++m){
            float2 a = xp[m], bb = xp[23-m];
            u[m-1] = cadd_(a, bb);
            d[m-1] = csub_(a, bb);
        }
        __syncthreads();
        int k2beg = qr*6;
        int k2end = (qr == 3) ? 23 : k2beg + 6;
        for (int k2 = k2beg; k2 < k2end; ++k2){
            const float2* row = F23P + k2*11;      // wave-uniform -> s_load
            float re = x0.x, im = x0.y;
            #pragma unroll
            for (int m = 0; m < 11; ++m){
                float c = row[m].x, s = row[m].y;
                re += u[m].x*c - d[m].y*s;
                im += u[m].y*c + d[m].x*s;
            }
            X[ll*369 + k1 + 16*k2] = make_float2(re, im);
        }
    }
    __syncthreads();

    // Phase 3c: transposed store Bt[(b*368+k)*640 + h0 + l]
    const float sc = 0.052129458158616354f;        // 1/sqrt(368)
    for (int i = t; i < FROWS*368; i += 256){
        int k = i >> 2, ll = i & 3;
        float2 v = X[ll*369 + k];
        float s = (k & 1) ? -sc : sc;              // (-1)^k
        Bt[((size_t)(b*368 + k))*640 + h0 + ll] = make_float2(v.x*s, v.y*s);
    }
}

// ---------------------------------------------------------------------------
// K2: H-axis centered IFFT, H = 640 = 16*8*5.  Line-major over Bt[b][w][h];
// output A2[b][w][h] contiguous. Fully coalesced global IO.  736 blocks.
// ---------------------------------------------------------------------------
__global__ __launch_bounds__(256) void fftH_kernel(const float2* __restrict__ Bt,
                                                   const float2* __restrict__ TW640P,
                                                   const float2* __restrict__ TW40P,
                                                   float2* __restrict__ A2){
    __shared__ float2 X[HLINES*HP];       // 20,640 B
    int t = threadIdx.x;
    size_t base = (size_t)blockIdx.x * (HLINES*640);

    for (int i = t; i < HLINES*640; i += 256){
        int l = i / 640, n = i - l*640;
        float2 v = Bt[base + i];
        float s = (n & 1) ? -1.f : 1.f;            // (-1)^n
        X[l*HP + n] = make_float2(v.x*s, v.y*s);
    }
    __syncthreads();

    // stage 1: FFT16 over n1, items (l,n2) = 160
    if (t < 160){
        int l = t & 3, n2 = t >> 2;
        float2 xr[16], Xo[16];
        #pragma unroll
        for (int n1 = 0; n1 < 16; ++n1) xr[n1] = X[l*HP + 40*n1 + n2];
        fft16p_(xr, Xo);
        const float2* row = TW640P + n2*16;
        #pragma unroll
        for (int k1 = 0; k1 < 16; ++k1)
            X[l*HP + 40*k1 + n2] = cmulv_(Xo[k1], row[k1]);
    }
    __syncthreads();

    // stage 2a: FFT8 over m1, items (l,k1,m2) = 320
    for (int it = t; it < 320; it += 256){
        int l = it & 3, k1 = (it >> 2) & 15, m2 = it >> 6;
        float2 xr[8], Xo[8];
        #pragma unroll
        for (int m1 = 0; m1 < 8; ++m1) xr[m1] = X[l*HP + 40*k1 + 5*m1 + m2];
        fft8p_(xr, Xo);
        const float2* row = TW40P + m2*8;
        #pragma unroll
        for (int j1 = 0; j1 < 8; ++j1)
            X[l*HP + 40*k1 + 5*j1 + m2] = cmulv_(Xo[j1], row[j1]);
    }
    __syncthreads();

    // stage 2b: DFT5 over m2 via pairs, items (l,k1,j1) = 512 -> 2/thread
    {
        const float CK1[5] = {1.f,  0.30901699437494745f, -0.8090169943749475f, -0.8090169943749475f,  0.30901699437494745f};
        const float SK1[5] = {0.f,  0.9510565162951535f,   0.5877852522924731f, -0.5877852522924731f, -0.9510565162951535f};
        const float CK2[5] = {1.f, -0.8090169943749475f,   0.30901699437494745f, 0.30901699437494745f, -0.8090169943749475f};
        const float SK2[5] = {0.f,  0.5877852522924731f,  -0.9510565162951535f,  0.9510565162951535f, -0.5877852522924731f};
        int it0 = t, it1 = t + 256;
        int l0 = it0 & 3, k10 = (it0 >> 2) & 15, j10 = it0 >> 6;
        int l1 = it1 & 3, k11 = (it1 >> 2) & 15, j11 = it1 >> 6;
        float2 p0[5], p1[5];
        #pragma unroll
        for (int m2 = 0; m2 < 5; ++m2) p0[m2] = X[l0*HP + 40*k10 + 5*j10 + m2];
        #pragma unroll
        for (int m2 = 0; m2 < 5; ++m2) p1[m2] = X[l1*HP + 40*k11 + 5*j11 + m2];
        __syncthreads();
        float2 u0a = cadd_(p0[1], p0[4]), d0a = csub_(p0[1], p0[4]);
        float2 u0b = cadd_(p0[2], p0[3]), d0b = csub_(p0[2], p0[3]);
        float2 u1a = cadd_(p1[1], p1[4]), d1a = csub_(p1[1], p1[4]);
        float2 u1b = cadd_(p1[2], p1[3]), d1b = csub_(p1[2], p1[3]);
        #pragma unroll
        for (int j2 = 0; j2 < 5; ++j2){
            float c1v = CK1[j2], s1v = SK1[j2], c2v = CK2[j2], s2v = SK2[j2];
            float re0 = p0[0].x + u0a.x*c1v - d0a.y*s1v + u0b.x*c2v - d0b.y*s2v;
            float im0 = p0[0].y + u0a.y*c1v + d0a.x*s1v + u0b.y*c2v + d0b.x*s2v;
            float re1 = p1[0].x + u1a.x*c1v - d1a.y*s1v + u1b.x*c2v - d1b.y*s2v;
            float im1 = p1[0].y + u1a.y*c1v + d1a.x*s1v + u1b.y*c2v + d1b.x*s2v;
            X[l0*HP + k10 + 16*j10 + 128*j2] = make_float2(re0, im0);
            X[l1*HP + k11 + 16*j11 + 128*j2] = make_float2(re1, im1);
        }
    }
    __syncthreads();

    const float sc = 0.03952847075210474f;         // 1/sqrt(640)
    for (int i = t; i < HLINES*640; i += 256){
        int l = i / 640, k = i - l*640;
        float2 v = X[l*HP + k];
        float s = (k & 1) ? -sc : sc;              // (-1)^k
        A2[base + i] = make_float2(v.x*s, v.y*s);
    }
}

// ---------------------------------------------------------------------------
// K3 (fused tail): B-axis FFT8 + magnitude + fp16-emulated conv2(1x1) + leaky
//                  + conv3x3(1->1, pad1) + leaky -> d_out.
// ---------------------------------------------------------------------------
__global__ __launch_bounds__(256) void tail_kernel(const float2* __restrict__ A2,
                                  const float* __restrict__ img,
                                  const float* __restrict__ w2,
                                  const float* __restrict__ b2,
                                  const float* __restrict__ wi,
                                  const float* __restrict__ bi,
                                  float* __restrict__ out){
    __shared__ float Pl[8][TS+2][TS+3];            // pitch 19: 2-way banks
    int t = threadIdx.x;
    int ty0 = (blockIdx.x / 23) * TS;              // 40 tiles over h
    int tx0 = (blockIdx.x % 23) * TS;              // 23 tiles over w

    float w2h0 = __half2float(__float2half(w2[0]));
    float w2h1 = __half2float(__float2half(w2[1]));
    float b2h  = __half2float(__float2half(b2[0]));
    const float sc8 = 0.35355339059327373f;        // 1/sqrt(8)

    // pass 1a: |centered ifft8| from A2, lanes sweep h (coalesced runs)
    for (int idx = t; idx < (TS+2)*(TS+2); idx += 256){
        int hx = idx / (TS+2), hy = idx - hx*(TS+2);
        int hh = ty0 - 1 + hy, ww = tx0 - 1 + hx;
        int hc = min(max(hh, 0), H_-1), wc = min(max(ww, 0), W_-1);
        float2 x[8], Xo[8];
        #pragma unroll
        for (int n = 0; n < 8; ++n){
            float2 v = A2[((size_t)(n*368 + wc))*640 + hc];
            float s = (n & 1) ? -1.f : 1.f;        // (-1)^n
            x[n] = make_float2(v.x*s, v.y*s);
        }
        fft8p_(x, Xo);
        #pragma unroll
        for (int k = 0; k < 8; ++k){
            float s = (k & 1) ? -sc8 : sc8;        // (-1)^k / sqrt(8)
            float yr = Xo[k].x * s, yi = Xo[k].y * s;
            float mag = sqrtf(yr*yr + yi*yi);
            Pl[k][hy][hx] = __half2float(__float2half(mag));
        }
    }
    __syncthreads();

    // pass 1b: conv2 with img, lanes sweep w (coalesced img reads)
    for (int idx = t; idx < (TS+2)*(TS+2); idx += 256){
        int hy = idx / (TS+2), hx = idx - hy*(TS+2);
        int hh = ty0 - 1 + hy, ww = tx0 - 1 + hx;
        bool inb = (hh >= 0) && (hh < H_) && (ww >= 0) && (ww < W_);
        int hc = min(max(hh, 0), H_-1), wc = min(max(ww, 0), W_-1);
        float inbf = inb ? 1.f : 0.f;
        #pragma unroll
        for (int k = 0; k < 8; ++k){
            float g = __half2float(__float2half(img[(size_t)k*HW_ + hc*W_ + wc]));
            float a = Pl[k][hy][hx];
            float o = leaky_(a*w2h0 + g*w2h1 + b2h);
            o = __half2float(__float2half(o));
            Pl[k][hy][hx] = o * inbf;              // zero-pad outside image
        }
    }
    __syncthreads();

    // stage 2: conv3x3 from LDS, 256 spatial px x 8 batch per block
    int sy = t >> 4, sx = t & 15;
    float wv[9];
    #pragma unroll
    for (int q = 0; q < 9; ++q) wv[q] = wi[q];
    float bi0 = bi[0];
    #pragma unroll
    for (int k = 0; k < 8; ++k){
        float acc = bi0;
        #pragma unroll
        for (int dy = 0; dy < 3; ++dy)
            #pragma unroll
            for (int dx = 0; dx < 3; ++dx)
                acc += wv[dy*3+dx] * Pl[k][sy+dy][sx+dx];
        out[((size_t)k*H_ + ty0+sy)*W_ + tx0+sx] = leaky_(acc);
    }
}

// ---------------------------------------------------------------------------
// Workspace layout (bytes):
//   Bt     : float2[NP]    @ 0            (15,073,280)   [b][w][h]
//   A2     : float2[NP]    @ 15,073,280   (15,073,280)   [b][w][h]
//   tables : float2[1301]  @ 30,146,560   (10,408)
// ---------------------------------------------------------------------------
extern "C" void kernel_launch(void* const* d_in, const int* in_sizes, int n_in,
                              void* d_out, int out_size, void* d_ws, size_t ws_size,
                              hipStream_t stream){
    const float* img = (const float*)d_in[0];
    const float* ksp = (const float*)d_in[1];
    const float* wk  = (const float*)d_in[2];
    const float* bk  = (const float*)d_in[3];
    const float* w1  = (const float*)d_in[4];
    const float* b1  = (const float*)d_in[5];
    const float* w2  = (const float*)d_in[6];
    const float* b2  = (const float*)d_in[7];
    const float* wi  = (const float*)d_in[8];
    const float* bi  = (const float*)d_in[9];

    char* ws = (char*)d_ws;
    float2* Bt  = (float2*)(ws + 0);
    float2* A2  = (float2*)(ws + 15073280);
    float2* T   = (float2*)(ws + 30146560);
    float2* TW368P = T + 0;
    float2* TW640P = T + 368;
    float2* TW40P  = T + 1008;
    float2* F23P   = T + 1048;
    float* out  = (float*)d_out;

    init_tables_kernel<<<6, 256, 0, stream>>>(T);

    kfftw_kernel<<<B_*(H_/FROWS), 256, 0, stream>>>(ksp, wk, bk, w1, b1,
                                                    TW368P, F23P, Bt);
    fftH_kernel<<<(B_*W_)/HLINES, 256, 0, stream>>>(Bt, TW640P, TW40P, A2);
    tail_kernel<<<(H_/TS)*(W_/TS), 256, 0, stream>>>(A2, img, w2, b2, wi, bi, out);
}